// Round 1
// baseline (3352.490 us; speedup 1.0000x reference)
//
#include <hip/hip_runtime.h>

#define H 128
#define LDP 132   // LDS row pitch in floats: 16B-aligned, breaks power-of-2 bank stride
#define NN 64     // nodes per batch graph

__device__ __forceinline__ float silu_f(float v) {
  return v * (1.0f / (1.0f + __expf(-v)));
}

// Register-tiled GEMM: acc[RPT][8] += A_lds[r0+rr][0:128] @ Wg[0:128][c0:c0+8]
// A is an LDS tile with row pitch LDP. Wg is global (L1/L2-broadcast across WGs).
template<int RPT>
__device__ __forceinline__ void gemm_acc(const float* A, const float* __restrict__ Wg,
                                         float (&acc)[RPT][8], int r0, int c0) {
#pragma unroll 4
  for (int k = 0; k < H; k += 4) {
    float4 av[RPT];
#pragma unroll
    for (int rr = 0; rr < RPT; ++rr)
      av[rr] = *(const float4*)(A + (r0 + rr) * LDP + k);
#pragma unroll
    for (int kk = 0; kk < 4; ++kk) {
      const float* wrow = Wg + (k + kk) * H + c0;
      float4 w0 = *(const float4*)(wrow);
      float4 w1 = *(const float4*)(wrow + 4);
#pragma unroll
      for (int rr = 0; rr < RPT; ++rr) {
        float a = (kk == 0) ? av[rr].x : (kk == 1) ? av[rr].y : (kk == 2) ? av[rr].z : av[rr].w;
        acc[rr][0] = fmaf(a, w0.x, acc[rr][0]);
        acc[rr][1] = fmaf(a, w0.y, acc[rr][1]);
        acc[rr][2] = fmaf(a, w0.z, acc[rr][2]);
        acc[rr][3] = fmaf(a, w0.w, acc[rr][3]);
        acc[rr][4] = fmaf(a, w1.x, acc[rr][4]);
        acc[rr][5] = fmaf(a, w1.y, acc[rr][5]);
        acc[rr][6] = fmaf(a, w1.z, acc[rr][6]);
        acc[rr][7] = fmaf(a, w1.w, acc[rr][7]);
      }
    }
  }
}

// h init + pos copy. grid 4096 x 256 covers 8192*128 exactly.
__global__ void init_kernel(const float* __restrict__ x, const float* __restrict__ ne,
                            float* __restrict__ h, float* __restrict__ pos0,
                            float* __restrict__ posA) {
  int g = blockIdx.x * 256 + threadIdx.x;
  h[g] = ne[g & (H - 1)];
  if (g < 24576) { pos0[g] = x[g]; posA[g] = x[g]; }
}

// Per-node projections: hs = h@W1a, hd = h@W1b + b1, hn = h@Wn1a + bn1
// grid = 128 row-blocks * 3 outputs
__global__ __launch_bounds__(256) void proj_kernel(
    const float* __restrict__ h, const float* __restrict__ ew1,
    const float* __restrict__ eb1, const float* __restrict__ nw1,
    const float* __restrict__ nb1, float* __restrict__ hs,
    float* __restrict__ hd, float* __restrict__ hn) {
  __shared__ float As[NN * LDP];
  const int tid = threadIdx.x;
  const int rb = blockIdx.x & 127;
  const int wsel = blockIdx.x >> 7;
  const int rowbase = rb * NN;
  for (int f = tid; f < NN * H / 4; f += 256) {
    int row = f >> 5, c4 = (f & 31) << 2;
    *(float4*)(As + row * LDP + c4) = *(const float4*)(h + (size_t)(rowbase + row) * H + c4);
  }
  __syncthreads();
  const float* W; const float* bias; float* out;
  if (wsel == 0)      { W = ew1;          bias = nullptr; out = hs; }
  else if (wsel == 1) { W = ew1 + H * H;  bias = eb1;     out = hd; }
  else                { W = nw1;          bias = nb1;     out = hn; }
  const int tx = tid & 15, ty = tid >> 4;
  const int c0 = tx * 8, r0 = ty * 4;
  float acc[4][8] = {};
  gemm_acc<4>(As, W, acc, r0, c0);
#pragma unroll
  for (int rr = 0; rr < 4; ++rr) {
#pragma unroll
    for (int cc = 0; cc < 8; ++cc) {
      float v = acc[rr][cc] + (bias ? bias[c0 + cc] : 0.0f);
      out[(size_t)(rowbase + r0 + rr) * H + c0 + cc] = v;
    }
  }
}

// One WG per (batch, dst). Fused: t1 build -> edge MLP2 -> coord MLP -> local segment sums.
__global__ __launch_bounds__(256) void edge_kernel(
    const float* __restrict__ hs, const float* __restrict__ hd,
    const float* __restrict__ w1c, const float* __restrict__ W2,
    const float* __restrict__ b2, const float* __restrict__ Wc1,
    const float* __restrict__ bc1, const float* __restrict__ wc2,
    const float* __restrict__ pos_in, float* __restrict__ pos_out,
    float* __restrict__ msg) {
  __shared__ float t1s[NN * LDP];   // t1, later reused as t2
  __shared__ float ms[NN * LDP];    // m
  __shared__ float relc[3][NN];
  __shared__ float d2s[NN];
  __shared__ float cws[NN];
  __shared__ float hdj[H];
  __shared__ float w1cs[H];
  __shared__ float posjs[3];

  const int tid = threadIdx.x;
  const int b = blockIdx.x >> 6;
  const int j = blockIdx.x & 63;
  const int nb = b * NN;

  // stage pos (192 floats) into t1s temporarily
  if (tid < 192) t1s[tid] = pos_in[(size_t)nb * 3 + tid];
  __syncthreads();
  if (tid < NN) {
    float px = t1s[tid * 3], py = t1s[tid * 3 + 1], pz = t1s[tid * 3 + 2];
    float qx = t1s[j * 3],  qy = t1s[j * 3 + 1],  qz = t1s[j * 3 + 2];
    float rx = px - qx, ry = py - qy, rz = pz - qz;
    relc[0][tid] = rx; relc[1][tid] = ry; relc[2][tid] = rz;
    d2s[tid] = rx * rx + ry * ry + rz * rz;
  } else if (tid < NN + 3) {
    posjs[tid - NN] = t1s[j * 3 + (tid - NN)];
  }
  if (tid >= 128) w1cs[tid - 128] = w1c[tid - 128];
  else hdj[tid] = hd[(size_t)(nb + j) * H + tid];
  __syncthreads();

  // Phase B: t1[i][c] = silu(hs[i][c] + hd_j[c] + d2_i * w1c[c])
  {
    const int c = tid & (H - 1);
    const int ii0 = tid >> 7;
    float hdv = hdj[c], w1v = w1cs[c];
    for (int i = ii0; i < NN; i += 2) {
      float v = hs[(size_t)(nb + i) * H + c] + hdv + d2s[i] * w1v;
      t1s[i * LDP + c] = silu_f(v);
    }
  }
  __syncthreads();

  const int tx = tid & 15, ty = tid >> 4;
  const int c0 = tx * 8, r0 = ty * 4;

  // Phase C: m = silu(t1 @ W2 + b2)
  {
    float acc[4][8] = {};
    gemm_acc<4>(t1s, W2, acc, r0, c0);
#pragma unroll
    for (int rr = 0; rr < 4; ++rr) {
#pragma unroll
      for (int cc = 0; cc < 8; ++cc) {
        float v = acc[rr][cc] + b2[c0 + cc];
        ms[(r0 + rr) * LDP + c0 + cc] = silu_f(v);
      }
    }
  }
  __syncthreads();

  // Phase D: t2 = silu(m @ Wc1 + bc1); cw[i] = t2 . wc2
  {
    float acc2[4][8] = {};
    gemm_acc<4>(ms, Wc1, acc2, r0, c0);
    float4 wv0 = *(const float4*)(wc2 + c0);
    float4 wv1 = *(const float4*)(wc2 + c0 + 4);
#pragma unroll
    for (int rr = 0; rr < 4; ++rr) {
      float s = 0.0f;
      s += silu_f(acc2[rr][0] + bc1[c0 + 0]) * wv0.x;
      s += silu_f(acc2[rr][1] + bc1[c0 + 1]) * wv0.y;
      s += silu_f(acc2[rr][2] + bc1[c0 + 2]) * wv0.z;
      s += silu_f(acc2[rr][3] + bc1[c0 + 3]) * wv0.w;
      s += silu_f(acc2[rr][4] + bc1[c0 + 4]) * wv1.x;
      s += silu_f(acc2[rr][5] + bc1[c0 + 5]) * wv1.y;
      s += silu_f(acc2[rr][6] + bc1[c0 + 6]) * wv1.z;
      s += silu_f(acc2[rr][7] + bc1[c0 + 7]) * wv1.w;
      // reduce across the 16 tx lanes (lanes ty*16+tx are consecutive in the wave)
      for (int mlane = 8; mlane >= 1; mlane >>= 1) s += __shfl_xor(s, mlane);
      if (tx == 0) cws[r0 + rr] = s;
    }
  }
  __syncthreads();

  // Phase E: local segment sums (dst == j owns all its edges)
  if (tid < H) {
    float s = 0.0f;
    for (int i = 0; i < NN; ++i) s += ms[i * LDP + tid];
    s -= ms[j * LDP + tid];   // exclude i == j (not a real edge)
    msg[(size_t)(nb + j) * H + tid] = s;
  } else if (tid < H + 3) {
    int comp = tid - H;
    float s = 0.0f;
    for (int i = 0; i < NN; ++i) s = fmaf(relc[comp][i], cws[i], s);  // rel[j]=0, self-safe
    pos_out[(size_t)(nb + j) * 3 + comp] = posjs[comp] + s;
  }
}

// h += silu(hn + msg@Wn1b) @ Wn2 + bn2 ; row-local, in-place on h. 256 WGs x 32 rows.
__global__ __launch_bounds__(256) void node_kernel(
    const float* __restrict__ msg, const float* __restrict__ hn,
    const float* __restrict__ nw1b, const float* __restrict__ nw2,
    const float* __restrict__ nb2, float* __restrict__ h) {
  __shared__ float As[32 * LDP];
  __shared__ float Bs[32 * LDP];
  __shared__ float Us[32 * LDP];
  const int tid = threadIdx.x;
  const int rowbase = blockIdx.x * 32;
  for (int f = tid; f < 32 * H / 4; f += 256) {
    int row = f >> 5, c4 = (f & 31) << 2;
    *(float4*)(As + row * LDP + c4) = *(const float4*)(msg + (size_t)(rowbase + row) * H + c4);
    *(float4*)(Bs + row * LDP + c4) = *(const float4*)(hn + (size_t)(rowbase + row) * H + c4);
  }
  __syncthreads();
  const int tx = tid & 15, ty = tid >> 4;
  const int c0 = tx * 8, r0 = ty * 2;
  {
    float acc[2][8] = {};
    gemm_acc<2>(As, nw1b, acc, r0, c0);
#pragma unroll
    for (int rr = 0; rr < 2; ++rr)
#pragma unroll
      for (int cc = 0; cc < 8; ++cc)
        Us[(r0 + rr) * LDP + c0 + cc] =
            silu_f(acc[rr][cc] + Bs[(r0 + rr) * LDP + c0 + cc]);
  }
  __syncthreads();
  {
    float acc2[2][8] = {};
    gemm_acc<2>(Us, nw2, acc2, r0, c0);
#pragma unroll
    for (int rr = 0; rr < 2; ++rr)
#pragma unroll
      for (int cc = 0; cc < 8; ++cc) {
        size_t idx = (size_t)(rowbase + r0 + rr) * H + c0 + cc;
        h[idx] += acc2[rr][cc] + nb2[c0 + cc];
      }
  }
}

// dx = pos - pos0, mean-centered over the 64 nodes of each batch, scaled.
__global__ void out_kernel(const float* __restrict__ posF, const float* __restrict__ pos0,
                           const float* __restrict__ scale, float* __restrict__ out) {
  int b = blockIdx.x, i = threadIdx.x;  // 64 threads = 1 wave
  int n = b * NN + i;
  float d0 = posF[n * 3]     - pos0[n * 3];
  float d1 = posF[n * 3 + 1] - pos0[n * 3 + 1];
  float d2v = posF[n * 3 + 2] - pos0[n * 3 + 2];
  float s0 = d0, s1 = d1, s2 = d2v;
  for (int m = 32; m; m >>= 1) {
    s0 += __shfl_xor(s0, m);
    s1 += __shfl_xor(s1, m);
    s2 += __shfl_xor(s2, m);
  }
  const float inv = 1.0f / 64.0f;
  float sc = scale[0];
  out[b * 192 + i * 3]     = (d0 - s0 * inv) * sc;
  out[b * 192 + i * 3 + 1] = (d1 - s1 * inv) * sc;
  out[b * 192 + i * 3 + 2] = (d2v - s2 * inv) * sc;
}

extern "C" void kernel_launch(void* const* d_in, const int* in_sizes, int n_in,
                              void* d_out, int out_size, void* d_ws, size_t ws_size,
                              hipStream_t stream) {
  (void)in_sizes; (void)n_in; (void)out_size; (void)ws_size;
  const float* x   = (const float*)d_in[0];
  const float* ne  = (const float*)d_in[1];
  const float* osc = (const float*)d_in[2];
  const float* ew1 = (const float*)d_in[3];
  const float* eb1 = (const float*)d_in[4];
  const float* ew2 = (const float*)d_in[5];
  const float* eb2 = (const float*)d_in[6];
  const float* cw1 = (const float*)d_in[7];
  const float* cb1 = (const float*)d_in[8];
  const float* cw2 = (const float*)d_in[9];
  const float* nw1 = (const float*)d_in[10];
  const float* nb1 = (const float*)d_in[11];
  const float* nw2 = (const float*)d_in[12];
  const float* nb2 = (const float*)d_in[13];
  // d_in[14] = edge_index: fully-connected structure is generated in-kernel.

  float* ws = (float*)d_ws;
  float* pos0 = ws;                    // 8192*3
  float* posA = pos0 + 24576;
  float* posB = posA + 24576;
  float* h    = posB + 24576;          // 8192*128
  float* hsb  = h   + 1048576;
  float* hdb  = hsb + 1048576;
  float* hnb  = hdb + 1048576;
  float* msgb = hnb + 1048576;

  init_kernel<<<4096, 256, 0, stream>>>(x, ne, h, pos0, posA);

  const float* pin[4]  = {posA, posB, posA, posB};
  float*       pout[4] = {posB, posA, posB, posA};

  for (int l = 0; l < 4; ++l) {
    const float* ew1l = ew1 + (size_t)l * 257 * H;
    proj_kernel<<<384, 256, 0, stream>>>(h, ew1l, eb1 + l * H,
                                         nw1 + (size_t)l * 256 * H, nb1 + l * H,
                                         hsb, hdb, hnb);
    edge_kernel<<<8192, 256, 0, stream>>>(hsb, hdb, ew1l + 256 * H,
                                          ew2 + (size_t)l * H * H, eb2 + l * H,
                                          cw1 + (size_t)l * H * H, cb1 + l * H,
                                          cw2 + (size_t)l * H,
                                          pin[l], pout[l], msgb);
    node_kernel<<<256, 256, 0, stream>>>(msgb, hnb,
                                         nw1 + (size_t)l * 256 * H + H * H,
                                         nw2 + (size_t)l * H * H, nb2 + l * H, h);
  }
  out_kernel<<<128, 64, 0, stream>>>(posA, pos0, osc, (float*)d_out);
}

// Round 2
// 2671.193 us; speedup vs baseline: 1.2551x; 1.2551x over previous
//
#include <hip/hip_runtime.h>

#define H 128
#define LDP 132   // LDS row pitch in floats: 16B-aligned, breaks power-of-2 bank stride
#define NN 64     // nodes per batch graph

__device__ __forceinline__ float silu_f(float v) {
  return v * (1.0f / (1.0f + __expf(-v)));
}

// Register-tiled GEMM: acc[RPT][8] += A_lds[r0+rr][0:128] @ Wg[0:128][c0:c0+8]
// A is an LDS tile with row pitch LDP. Wg is global (L1/L2-broadcast across WGs).
template<int RPT>
__device__ __forceinline__ void gemm_acc(const float* A, const float* __restrict__ Wg,
                                         float (&acc)[RPT][8], int r0, int c0) {
#pragma unroll 4
  for (int k = 0; k < H; k += 4) {
    float4 av[RPT];
#pragma unroll
    for (int rr = 0; rr < RPT; ++rr)
      av[rr] = *(const float4*)(A + (r0 + rr) * LDP + k);
#pragma unroll
    for (int kk = 0; kk < 4; ++kk) {
      const float* wrow = Wg + (k + kk) * H + c0;
      float4 w0 = *(const float4*)(wrow);
      float4 w1 = *(const float4*)(wrow + 4);
#pragma unroll
      for (int rr = 0; rr < RPT; ++rr) {
        float a = (kk == 0) ? av[rr].x : (kk == 1) ? av[rr].y : (kk == 2) ? av[rr].z : av[rr].w;
        acc[rr][0] = fmaf(a, w0.x, acc[rr][0]);
        acc[rr][1] = fmaf(a, w0.y, acc[rr][1]);
        acc[rr][2] = fmaf(a, w0.z, acc[rr][2]);
        acc[rr][3] = fmaf(a, w0.w, acc[rr][3]);
        acc[rr][4] = fmaf(a, w1.x, acc[rr][4]);
        acc[rr][5] = fmaf(a, w1.y, acc[rr][5]);
        acc[rr][6] = fmaf(a, w1.z, acc[rr][6]);
        acc[rr][7] = fmaf(a, w1.w, acc[rr][7]);
      }
    }
  }
}

// h init + pos copy. grid 4096 x 256 covers 8192*128 exactly.
__global__ void init_kernel(const float* __restrict__ x, const float* __restrict__ ne,
                            float* __restrict__ h, float* __restrict__ pos0,
                            float* __restrict__ posA) {
  int g = blockIdx.x * 256 + threadIdx.x;
  h[g] = ne[g & (H - 1)];
  if (g < 24576) { pos0[g] = x[g]; posA[g] = x[g]; }
}

// Per-node projections: hs = h@W1a, hd = h@W1b + b1, hn = h@Wn1a + bn1
// grid = 128 row-blocks * 3 outputs
__global__ __launch_bounds__(256) void proj_kernel(
    const float* __restrict__ h, const float* __restrict__ ew1,
    const float* __restrict__ eb1, const float* __restrict__ nw1,
    const float* __restrict__ nb1, float* __restrict__ hs,
    float* __restrict__ hd, float* __restrict__ hn) {
  __shared__ float As[NN * LDP];
  const int tid = threadIdx.x;
  const int rb = blockIdx.x & 127;
  const int wsel = blockIdx.x >> 7;
  const int rowbase = rb * NN;
  for (int f = tid; f < NN * H / 4; f += 256) {
    int row = f >> 5, c4 = (f & 31) << 2;
    *(float4*)(As + row * LDP + c4) = *(const float4*)(h + (size_t)(rowbase + row) * H + c4);
  }
  __syncthreads();
  const float* W; const float* bias; float* out;
  if (wsel == 0)      { W = ew1;          bias = nullptr; out = hs; }
  else if (wsel == 1) { W = ew1 + H * H;  bias = eb1;     out = hd; }
  else                { W = nw1;          bias = nb1;     out = hn; }
  const int tx = tid & 15, ty = tid >> 4;
  const int c0 = tx * 8, r0 = ty * 4;
  float acc[4][8] = {};
  gemm_acc<4>(As, W, acc, r0, c0);
#pragma unroll
  for (int rr = 0; rr < 4; ++rr) {
#pragma unroll
    for (int cc = 0; cc < 8; ++cc) {
      float v = acc[rr][cc] + (bias ? bias[c0 + cc] : 0.0f);
      out[(size_t)(rowbase + r0 + rr) * H + c0 + cc] = v;
    }
  }
}

// One WG per (batch, dst). Fused: t1 build -> edge MLP2 -> coord MLP -> local segment sums.
// Single 64x132 LDS tile, reused: pos stage -> t1 -> m.  (~36 KB total -> 4 WG/CU)
__global__ __launch_bounds__(256) void edge_kernel(
    const float* __restrict__ hs, const float* __restrict__ hd,
    const float* __restrict__ w1c, const float* __restrict__ W2,
    const float* __restrict__ b2, const float* __restrict__ Wc1,
    const float* __restrict__ bc1, const float* __restrict__ wc2,
    const float* __restrict__ pos_in, float* __restrict__ pos_out,
    float* __restrict__ msg) {
  __shared__ float t1s[NN * LDP];   // pos stage -> t1 -> m
  __shared__ float relc[3][NN];
  __shared__ float d2s[NN];
  __shared__ float cws[NN];
  __shared__ float hdj[H];
  __shared__ float w1cs[H];
  __shared__ float posjs[3];

  const int tid = threadIdx.x;
  const int b = blockIdx.x >> 6;
  const int j = blockIdx.x & 63;
  const int nb = b * NN;

  // stage pos (192 floats) into t1s temporarily
  if (tid < 192) t1s[tid] = pos_in[(size_t)nb * 3 + tid];
  __syncthreads();
  if (tid < NN) {
    float px = t1s[tid * 3], py = t1s[tid * 3 + 1], pz = t1s[tid * 3 + 2];
    float qx = t1s[j * 3],  qy = t1s[j * 3 + 1],  qz = t1s[j * 3 + 2];
    float rx = px - qx, ry = py - qy, rz = pz - qz;
    relc[0][tid] = rx; relc[1][tid] = ry; relc[2][tid] = rz;
    d2s[tid] = rx * rx + ry * ry + rz * rz;
  } else if (tid < NN + 3) {
    posjs[tid - NN] = t1s[j * 3 + (tid - NN)];
  }
  if (tid >= 128) w1cs[tid - 128] = w1c[tid - 128];
  else hdj[tid] = hd[(size_t)(nb + j) * H + tid];
  __syncthreads();

  // Phase B: t1[i][c] = silu(hs[i][c] + hd_j[c] + d2_i * w1c[c])
  {
    const int c = tid & (H - 1);
    const int ii0 = tid >> 7;
    float hdv = hdj[c], w1v = w1cs[c];
    for (int i = ii0; i < NN; i += 2) {
      float v = hs[(size_t)(nb + i) * H + c] + hdv + d2s[i] * w1v;
      t1s[i * LDP + c] = silu_f(v);
    }
  }
  __syncthreads();

  const int tx = tid & 15, ty = tid >> 4;
  const int c0 = tx * 8, r0 = ty * 4;

  // Phase C: m = silu(t1 @ W2 + b2) -- GEMM into regs, then overwrite t1s with m
  {
    float acc[4][8] = {};
    gemm_acc<4>(t1s, W2, acc, r0, c0);
    __syncthreads();   // everyone done READING t1
#pragma unroll
    for (int rr = 0; rr < 4; ++rr) {
      float4 lo, hi;
      lo.x = silu_f(acc[rr][0] + b2[c0 + 0]);
      lo.y = silu_f(acc[rr][1] + b2[c0 + 1]);
      lo.z = silu_f(acc[rr][2] + b2[c0 + 2]);
      lo.w = silu_f(acc[rr][3] + b2[c0 + 3]);
      hi.x = silu_f(acc[rr][4] + b2[c0 + 4]);
      hi.y = silu_f(acc[rr][5] + b2[c0 + 5]);
      hi.z = silu_f(acc[rr][6] + b2[c0 + 6]);
      hi.w = silu_f(acc[rr][7] + b2[c0 + 7]);
      *(float4*)(t1s + (r0 + rr) * LDP + c0)     = lo;
      *(float4*)(t1s + (r0 + rr) * LDP + c0 + 4) = hi;
    }
  }
  __syncthreads();

  // Phase D: t2 = silu(m @ Wc1 + bc1); cw[i] = t2 . wc2   (m is in t1s)
  {
    float acc2[4][8] = {};
    gemm_acc<4>(t1s, Wc1, acc2, r0, c0);
    float4 wv0 = *(const float4*)(wc2 + c0);
    float4 wv1 = *(const float4*)(wc2 + c0 + 4);
#pragma unroll
    for (int rr = 0; rr < 4; ++rr) {
      float s = 0.0f;
      s += silu_f(acc2[rr][0] + bc1[c0 + 0]) * wv0.x;
      s += silu_f(acc2[rr][1] + bc1[c0 + 1]) * wv0.y;
      s += silu_f(acc2[rr][2] + bc1[c0 + 2]) * wv0.z;
      s += silu_f(acc2[rr][3] + bc1[c0 + 3]) * wv0.w;
      s += silu_f(acc2[rr][4] + bc1[c0 + 4]) * wv1.x;
      s += silu_f(acc2[rr][5] + bc1[c0 + 5]) * wv1.y;
      s += silu_f(acc2[rr][6] + bc1[c0 + 6]) * wv1.z;
      s += silu_f(acc2[rr][7] + bc1[c0 + 7]) * wv1.w;
      // reduce across the 16 tx lanes (lanes ty*16+tx are consecutive in the wave)
      for (int mlane = 8; mlane >= 1; mlane >>= 1) s += __shfl_xor(s, mlane);
      if (tx == 0) cws[r0 + rr] = s;
    }
  }
  __syncthreads();

  // Phase E: local segment sums (dst == j owns all its edges); m is in t1s
  if (tid < H) {
    float s = 0.0f;
    for (int i = 0; i < NN; ++i) s += t1s[i * LDP + tid];
    s -= t1s[j * LDP + tid];   // exclude i == j (not a real edge)
    msg[(size_t)(nb + j) * H + tid] = s;
  } else if (tid < H + 3) {
    int comp = tid - H;
    float s = 0.0f;
    for (int i = 0; i < NN; ++i) s = fmaf(relc[comp][i], cws[i], s);  // rel[j]=0, self-safe
    pos_out[(size_t)(nb + j) * 3 + comp] = posjs[comp] + s;
  }
}

// h += silu(hn + msg@Wn1b) @ Wn2 + bn2 ; row-local, in-place on h. 256 WGs x 32 rows.
__global__ __launch_bounds__(256) void node_kernel(
    const float* __restrict__ msg, const float* __restrict__ hn,
    const float* __restrict__ nw1b, const float* __restrict__ nw2,
    const float* __restrict__ nb2, float* __restrict__ h) {
  __shared__ float As[32 * LDP];
  __shared__ float Bs[32 * LDP];
  __shared__ float Us[32 * LDP];
  const int tid = threadIdx.x;
  const int rowbase = blockIdx.x * 32;
  for (int f = tid; f < 32 * H / 4; f += 256) {
    int row = f >> 5, c4 = (f & 31) << 2;
    *(float4*)(As + row * LDP + c4) = *(const float4*)(msg + (size_t)(rowbase + row) * H + c4);
    *(float4*)(Bs + row * LDP + c4) = *(const float4*)(hn + (size_t)(rowbase + row) * H + c4);
  }
  __syncthreads();
  const int tx = tid & 15, ty = tid >> 4;
  const int c0 = tx * 8, r0 = ty * 2;
  {
    float acc[2][8] = {};
    gemm_acc<2>(As, nw1b, acc, r0, c0);
#pragma unroll
    for (int rr = 0; rr < 2; ++rr)
#pragma unroll
      for (int cc = 0; cc < 8; ++cc)
        Us[(r0 + rr) * LDP + c0 + cc] =
            silu_f(acc[rr][cc] + Bs[(r0 + rr) * LDP + c0 + cc]);
  }
  __syncthreads();
  {
    float acc2[2][8] = {};
    gemm_acc<2>(Us, nw2, acc2, r0, c0);
#pragma unroll
    for (int rr = 0; rr < 2; ++rr)
#pragma unroll
      for (int cc = 0; cc < 8; ++cc) {
        size_t idx = (size_t)(rowbase + r0 + rr) * H + c0 + cc;
        h[idx] += acc2[rr][cc] + nb2[c0 + cc];
      }
  }
}

// dx = pos - pos0, mean-centered over the 64 nodes of each batch, scaled.
__global__ void out_kernel(const float* __restrict__ posF, const float* __restrict__ pos0,
                           const float* __restrict__ scale, float* __restrict__ out) {
  int b = blockIdx.x, i = threadIdx.x;  // 64 threads = 1 wave
  int n = b * NN + i;
  float d0 = posF[n * 3]     - pos0[n * 3];
  float d1 = posF[n * 3 + 1] - pos0[n * 3 + 1];
  float d2v = posF[n * 3 + 2] - pos0[n * 3 + 2];
  float s0 = d0, s1 = d1, s2 = d2v;
  for (int m = 32; m; m >>= 1) {
    s0 += __shfl_xor(s0, m);
    s1 += __shfl_xor(s1, m);
    s2 += __shfl_xor(s2, m);
  }
  const float inv = 1.0f / 64.0f;
  float sc = scale[0];
  out[b * 192 + i * 3]     = (d0 - s0 * inv) * sc;
  out[b * 192 + i * 3 + 1] = (d1 - s1 * inv) * sc;
  out[b * 192 + i * 3 + 2] = (d2v - s2 * inv) * sc;
}

extern "C" void kernel_launch(void* const* d_in, const int* in_sizes, int n_in,
                              void* d_out, int out_size, void* d_ws, size_t ws_size,
                              hipStream_t stream) {
  (void)in_sizes; (void)n_in; (void)out_size; (void)ws_size;
  const float* x   = (const float*)d_in[0];
  const float* ne  = (const float*)d_in[1];
  const float* osc = (const float*)d_in[2];
  const float* ew1 = (const float*)d_in[3];
  const float* eb1 = (const float*)d_in[4];
  const float* ew2 = (const float*)d_in[5];
  const float* eb2 = (const float*)d_in[6];
  const float* cw1 = (const float*)d_in[7];
  const float* cb1 = (const float*)d_in[8];
  const float* cw2 = (const float*)d_in[9];
  const float* nw1 = (const float*)d_in[10];
  const float* nb1 = (const float*)d_in[11];
  const float* nw2 = (const float*)d_in[12];
  const float* nb2 = (const float*)d_in[13];
  // d_in[14] = edge_index: fully-connected structure is generated in-kernel.

  float* ws = (float*)d_ws;
  float* pos0 = ws;                    // 8192*3
  float* posA = pos0 + 24576;
  float* posB = posA + 24576;
  float* h    = posB + 24576;          // 8192*128
  float* hsb  = h   + 1048576;
  float* hdb  = hsb + 1048576;
  float* hnb  = hdb + 1048576;
  float* msgb = hnb + 1048576;

  init_kernel<<<4096, 256, 0, stream>>>(x, ne, h, pos0, posA);

  const float* pin[4]  = {posA, posB, posA, posB};
  float*       pout[4] = {posB, posA, posB, posA};

  for (int l = 0; l < 4; ++l) {
    const float* ew1l = ew1 + (size_t)l * 257 * H;
    proj_kernel<<<384, 256, 0, stream>>>(h, ew1l, eb1 + l * H,
                                         nw1 + (size_t)l * 256 * H, nb1 + l * H,
                                         hsb, hdb, hnb);
    edge_kernel<<<8192, 256, 0, stream>>>(hsb, hdb, ew1l + 256 * H,
                                          ew2 + (size_t)l * H * H, eb2 + l * H,
                                          cw1 + (size_t)l * H * H, cb1 + l * H,
                                          cw2 + (size_t)l * H,
                                          pin[l], pout[l], msgb);
    node_kernel<<<256, 256, 0, stream>>>(msgb, hnb,
                                         nw1 + (size_t)l * 256 * H + H * H,
                                         nw2 + (size_t)l * H * H, nb2 + l * H, h);
  }
  out_kernel<<<128, 64, 0, stream>>>(posA, pos0, osc, (float*)d_out);
}

// Round 6
// 1281.289 us; speedup vs baseline: 2.6165x; 2.0848x over previous
//
#include <hip/hip_runtime.h>

#define H 128
#define LDP 132   // fp32 LDS row pitch for proj/node kernels
#define NN 64     // nodes per batch graph

typedef short bf8_t __attribute__((ext_vector_type(8)));   // 8 bf16 = 4 VGPRs (MFMA A/B frag)
typedef float f4_t  __attribute__((ext_vector_type(4)));   // MFMA C/D frag

__device__ __forceinline__ float silu_f(float v) {
  return v * (1.0f / (1.0f + __expf(-v)));
}
// fp32 -> bf16 (RNE), as raw ushort bits
__device__ __forceinline__ unsigned short f2bf(float f) {
  unsigned int u = __float_as_uint(f);
  u = (u + 0x7fffu + ((u >> 16) & 1u)) >> 16;
  return (unsigned short)u;
}
__device__ __forceinline__ float bf2f(unsigned short h) {
  return __uint_as_float(((unsigned int)h) << 16);
}

// ---------------- fp32 register-tiled GEMM (proj/node kernels) ----------------
template<int RPT>
__device__ __forceinline__ void gemm_acc(const float* A, const float* __restrict__ Wg,
                                         float (&acc)[RPT][8], int r0, int c0) {
#pragma unroll 4
  for (int k = 0; k < H; k += 4) {
    float4 av[RPT];
#pragma unroll
    for (int rr = 0; rr < RPT; ++rr)
      av[rr] = *(const float4*)(A + (r0 + rr) * LDP + k);
#pragma unroll
    for (int kk = 0; kk < 4; ++kk) {
      const float* wrow = Wg + (k + kk) * H + c0;
      float4 w0 = *(const float4*)(wrow);
      float4 w1 = *(const float4*)(wrow + 4);
#pragma unroll
      for (int rr = 0; rr < RPT; ++rr) {
        float a = (kk == 0) ? av[rr].x : (kk == 1) ? av[rr].y : (kk == 2) ? av[rr].z : av[rr].w;
        acc[rr][0] = fmaf(a, w0.x, acc[rr][0]);
        acc[rr][1] = fmaf(a, w0.y, acc[rr][1]);
        acc[rr][2] = fmaf(a, w0.z, acc[rr][2]);
        acc[rr][3] = fmaf(a, w0.w, acc[rr][3]);
        acc[rr][4] = fmaf(a, w1.x, acc[rr][4]);
        acc[rr][5] = fmaf(a, w1.y, acc[rr][5]);
        acc[rr][6] = fmaf(a, w1.z, acc[rr][6]);
        acc[rr][7] = fmaf(a, w1.w, acc[rr][7]);
      }
    }
  }
}

// h init + pos copy. grid 4096 x 256 covers 8192*128 exactly.
__global__ void init_kernel(const float* __restrict__ x, const float* __restrict__ ne,
                            float* __restrict__ h, float* __restrict__ pos0,
                            float* __restrict__ posA) {
  int g = blockIdx.x * 256 + threadIdx.x;
  h[g] = ne[g & (H - 1)];
  if (g < 24576) { pos0[g] = x[g]; posA[g] = x[g]; }
}

// Weight prep: transpose + split W2 and Wc1 of each layer into bf16 hi/lo planes.
// dst[(l*2+mat)*16384 + c*128 + k] = split(src[l][k][c]).  grid 512x256.
__global__ void prep_kernel(const float* __restrict__ ew2, const float* __restrict__ cw1,
                            unsigned short* __restrict__ whi, unsigned short* __restrict__ wlo) {
  int idx = blockIdx.x * 256 + threadIdx.x;
  int l = idx >> 15;
  int r = idx & 32767;
  int mat = r >> 14;
  int e = r & 16383;
  int k = e >> 7, c = e & 127;
  const float* src = mat ? cw1 : ew2;
  float w = src[(size_t)l * 16384 + k * 128 + c];
  unsigned short hi = f2bf(w);
  unsigned short lo = f2bf(w - bf2f(hi));
  size_t dst = (size_t)(l * 2 + mat) * 16384 + c * 128 + k;
  whi[dst] = hi;
  wlo[dst] = lo;
}

// Per-node projections: hs = h@W1a, hd = h@W1b + b1, hn = h@Wn1a + bn1
__global__ __launch_bounds__(256) void proj_kernel(
    const float* __restrict__ h, const float* __restrict__ ew1,
    const float* __restrict__ eb1, const float* __restrict__ nw1,
    const float* __restrict__ nb1, float* __restrict__ hs,
    float* __restrict__ hd, float* __restrict__ hn) {
  __shared__ float As[NN * LDP];
  const int tid = threadIdx.x;
  const int rb = blockIdx.x & 127;
  const int wsel = blockIdx.x >> 7;
  const int rowbase = rb * NN;
  for (int f = tid; f < NN * H / 4; f += 256) {
    int row = f >> 5, c4 = (f & 31) << 2;
    *(float4*)(As + row * LDP + c4) = *(const float4*)(h + (size_t)(rowbase + row) * H + c4);
  }
  __syncthreads();
  const float* W; const float* bias; float* out;
  if (wsel == 0)      { W = ew1;          bias = nullptr; out = hs; }
  else if (wsel == 1) { W = ew1 + H * H;  bias = eb1;     out = hd; }
  else                { W = nw1;          bias = nb1;     out = hn; }
  const int tx = tid & 15, ty = tid >> 4;
  const int c0 = tx * 8, r0 = ty * 4;
  float acc[4][8] = {};
  gemm_acc<4>(As, W, acc, r0, c0);
#pragma unroll
  for (int rr = 0; rr < 4; ++rr) {
#pragma unroll
    for (int cc = 0; cc < 8; ++cc) {
      float v = acc[rr][cc] + (bias ? bias[c0 + cc] : 0.0f);
      out[(size_t)(rowbase + r0 + rr) * H + c0 + cc] = v;
    }
  }
}

// Split-bf16 MFMA GEMM: acc[Mt][Nt] += A(64x128, LDS hi/lo swizzled planes) @ B(128x128,
// global transposed hi/lo planes). 3-product split: AhBh + AlBh + AhBl.
// Per wave: cols [wave*32, wave*32+32), all 64 rows.
__device__ __forceinline__ void gemm_mfma(
    const unsigned short* Ahi, const unsigned short* Alo,
    const unsigned short* __restrict__ Bhi, const unsigned short* __restrict__ Blo,
    f4_t (&acc)[4][2], int lane, int wave) {
  const int arow = lane & 15;
  const int kch = (lane >> 4) * 8;
  const int bcol = wave * 32 + (lane & 15);
#pragma unroll
  for (int Kt = 0; Kt < 4; ++Kt) {
    const int k0 = Kt * 32 + kch;
    bf8_t bh0 = *(const bf8_t*)(Bhi + (size_t)bcol * H + k0);
    bf8_t bl0 = *(const bf8_t*)(Blo + (size_t)bcol * H + k0);
    bf8_t bh1 = *(const bf8_t*)(Bhi + (size_t)(bcol + 16) * H + k0);
    bf8_t bl1 = *(const bf8_t*)(Blo + (size_t)(bcol + 16) * H + k0);
#pragma unroll
    for (int Mt = 0; Mt < 4; ++Mt) {
      int row = Mt * 16 + arow;
      int byte = (row * 256 + k0 * 2) ^ ((row & 7) << 4);
      bf8_t ah = *(const bf8_t*)((const char*)Ahi + byte);
      bf8_t al = *(const bf8_t*)((const char*)Alo + byte);
      acc[Mt][0] = __builtin_amdgcn_mfma_f32_16x16x32_bf16(ah, bh0, acc[Mt][0], 0, 0, 0);
      acc[Mt][1] = __builtin_amdgcn_mfma_f32_16x16x32_bf16(ah, bh1, acc[Mt][1], 0, 0, 0);
      acc[Mt][0] = __builtin_amdgcn_mfma_f32_16x16x32_bf16(al, bh0, acc[Mt][0], 0, 0, 0);
      acc[Mt][1] = __builtin_amdgcn_mfma_f32_16x16x32_bf16(al, bh1, acc[Mt][1], 0, 0, 0);
      acc[Mt][0] = __builtin_amdgcn_mfma_f32_16x16x32_bf16(ah, bl0, acc[Mt][0], 0, 0, 0);
      acc[Mt][1] = __builtin_amdgcn_mfma_f32_16x16x32_bf16(ah, bl1, acc[Mt][1], 0, 0, 0);
    }
  }
}

// One WG (4 waves) per (batch, dst). t1 build -> MFMA edge-MLP2 -> MFMA coord-MLP
// -> local segment sums. t1/m live in swizzled bf16 hi/lo LDS planes.
__global__ __launch_bounds__(256) void edge_kernel(
    const float* __restrict__ hs, const float* __restrict__ hd,
    const float* __restrict__ w1c,
    const unsigned short* __restrict__ w2t_hi, const unsigned short* __restrict__ w2t_lo,
    const unsigned short* __restrict__ wc1t_hi, const unsigned short* __restrict__ wc1t_lo,
    const float* __restrict__ b2, const float* __restrict__ bc1,
    const float* __restrict__ wc2,
    const float* __restrict__ pos_in, float* __restrict__ pos_out,
    float* __restrict__ msg) {
  __shared__ unsigned short Ahi[NN * H];   // 16 KB, XOR-swizzled rows
  __shared__ unsigned short Alo[NN * H];   // 16 KB
  __shared__ float posbuf[192];
  __shared__ float relc[3][NN];
  __shared__ float d2s[NN];
  __shared__ float cws[NN];
  __shared__ float hdj[H];
  __shared__ float w1cs[H];
  __shared__ float posjs[3];

  const int tid = threadIdx.x;
  const int lane = tid & 63, wave = tid >> 6;
  const int b = blockIdx.x >> 6;
  const int j = blockIdx.x & 63;
  const int nb = b * NN;

  // Phase A: stage pos, zero cws
  if (tid < 192) posbuf[tid] = pos_in[(size_t)nb * 3 + tid];
  else cws[tid - 192] = 0.0f;
  __syncthreads();
  if (tid < NN) {
    float px = posbuf[tid * 3], py = posbuf[tid * 3 + 1], pz = posbuf[tid * 3 + 2];
    float qx = posbuf[j * 3],   qy = posbuf[j * 3 + 1],   qz = posbuf[j * 3 + 2];
    float rx = px - qx, ry = py - qy, rz = pz - qz;
    relc[0][tid] = rx; relc[1][tid] = ry; relc[2][tid] = rz;
    d2s[tid] = rx * rx + ry * ry + rz * rz;
    if (tid < 3) posjs[tid] = posbuf[j * 3 + tid];
  } else if (tid < 128) {
    int c = tid - 64;
    w1cs[c] = w1c[c];
    w1cs[c + 64] = w1c[c + 64];
  } else {
    hdj[tid - 128] = hd[(size_t)(nb + j) * H + (tid - 128)];
  }
  __syncthreads();

  // Phase B: t1[i][c] = silu(hs[i][c] + hd_j[c] + d2_i*w1c[c]) -> split bf16 planes
  {
    const int c2 = lane * 2;
    float hd0 = hdj[c2], hd1 = hdj[c2 + 1];
    float w10 = w1cs[c2], w11 = w1cs[c2 + 1];
    for (int i = wave; i < NN; i += 4) {
      float2 hv = *(const float2*)(hs + (size_t)(nb + i) * H + c2);
      float d2v = d2s[i];
      float v0 = silu_f(hv.x + hd0 + d2v * w10);
      float v1 = silu_f(hv.y + hd1 + d2v * w11);
      unsigned short h0 = f2bf(v0), h1 = f2bf(v1);
      unsigned short l0 = f2bf(v0 - bf2f(h0)), l1 = f2bf(v1 - bf2f(h1));
      int byte = (i * 256 + c2 * 2) ^ ((i & 7) << 4);
      *(unsigned int*)((char*)Ahi + byte) = (unsigned int)h0 | ((unsigned int)h1 << 16);
      *(unsigned int*)((char*)Alo + byte) = (unsigned int)l0 | ((unsigned int)l1 << 16);
    }
  }
  __syncthreads();

  const int col0 = wave * 32 + (lane & 15);

  // Phase C: m = silu(t1 @ W2 + b2)  (MFMA), write m back over planes
  {
    f4_t acc[4][2];
#pragma unroll
    for (int m = 0; m < 4; ++m) {
      acc[m][0] = (f4_t){0.f, 0.f, 0.f, 0.f};
      acc[m][1] = (f4_t){0.f, 0.f, 0.f, 0.f};
    }
    gemm_mfma(Ahi, Alo, w2t_hi, w2t_lo, acc, lane, wave);
    __syncthreads();   // all A-reads of t1 done before overwrite
    float biasA = b2[col0], biasB = b2[col0 + 16];
#pragma unroll
    for (int Mt = 0; Mt < 4; ++Mt) {
#pragma unroll
      for (int r = 0; r < 4; ++r) {
        int row = Mt * 16 + (lane >> 4) * 4 + r;
        int rsw = (row & 7) << 4;
        float vA = silu_f(acc[Mt][0][r] + biasA);
        float vB = silu_f(acc[Mt][1][r] + biasB);
        unsigned short hA = f2bf(vA), hB = f2bf(vB);
        unsigned short lA = f2bf(vA - bf2f(hA)), lB = f2bf(vB - bf2f(hB));
        int byA = (row * 256 + col0 * 2) ^ rsw;
        int byB = (row * 256 + (col0 + 16) * 2) ^ rsw;
        *(unsigned short*)((char*)Ahi + byA) = hA;
        *(unsigned short*)((char*)Alo + byA) = lA;
        *(unsigned short*)((char*)Ahi + byB) = hB;
        *(unsigned short*)((char*)Alo + byB) = lB;
      }
    }
  }
  __syncthreads();

  // Phase D: t2 = silu(m @ Wc1 + bc1); cw[row] = t2 . wc2  (MFMA + reduce)
  {
    f4_t acc2[4][2];
#pragma unroll
    for (int m = 0; m < 4; ++m) {
      acc2[m][0] = (f4_t){0.f, 0.f, 0.f, 0.f};
      acc2[m][1] = (f4_t){0.f, 0.f, 0.f, 0.f};
    }
    gemm_mfma(Ahi, Alo, wc1t_hi, wc1t_lo, acc2, lane, wave);
    float bcA = bc1[col0], bcB = bc1[col0 + 16];
    float wcA = wc2[col0], wcB = wc2[col0 + 16];
#pragma unroll
    for (int Mt = 0; Mt < 4; ++Mt) {
#pragma unroll
      for (int r = 0; r < 4; ++r) {
        int row = Mt * 16 + (lane >> 4) * 4 + r;
        float p = silu_f(acc2[Mt][0][r] + bcA) * wcA
                + silu_f(acc2[Mt][1][r] + bcB) * wcB;
        p += __shfl_xor(p, 8);
        p += __shfl_xor(p, 4);
        p += __shfl_xor(p, 2);
        p += __shfl_xor(p, 1);
        if ((lane & 15) == 0) atomicAdd(&cws[row], p);
      }
    }
  }
  __syncthreads();

  // Phase E: local segment sums (dst == j owns all its edges)
  if (tid < H) {
    float s = 0.0f;
    for (int i = 0; i < NN; ++i) {
      int byte = (i * 256 + tid * 2) ^ ((i & 7) << 4);
      s += bf2f(*(const unsigned short*)((const char*)Ahi + byte))
         + bf2f(*(const unsigned short*)((const char*)Alo + byte));
    }
    int bj = (j * 256 + tid * 2) ^ ((j & 7) << 4);
    s -= bf2f(*(const unsigned short*)((const char*)Ahi + bj))
       + bf2f(*(const unsigned short*)((const char*)Alo + bj));   // exclude i==j
    msg[(size_t)(nb + j) * H + tid] = s;
  } else if (tid < H + 3) {
    int comp = tid - H;
    float s = 0.0f;
    for (int i = 0; i < NN; ++i) s = fmaf(relc[comp][i], cws[i], s);  // rel[j]=0, self-safe
    pos_out[(size_t)(nb + j) * 3 + comp] = posjs[comp] + s;
  }
}

// h += silu(hn + msg@Wn1b) @ Wn2 + bn2 ; row-local, in-place on h. 256 WGs x 32 rows.
__global__ __launch_bounds__(256) void node_kernel(
    const float* __restrict__ msg, const float* __restrict__ hn,
    const float* __restrict__ nw1b, const float* __restrict__ nw2,
    const float* __restrict__ nb2, float* __restrict__ h) {
  __shared__ float As[32 * LDP];
  __shared__ float Bs[32 * LDP];
  __shared__ float Us[32 * LDP];
  const int tid = threadIdx.x;
  const int rowbase = blockIdx.x * 32;
  for (int f = tid; f < 32 * H / 4; f += 256) {
    int row = f >> 5, c4 = (f & 31) << 2;
    *(float4*)(As + row * LDP + c4) = *(const float4*)(msg + (size_t)(rowbase + row) * H + c4);
    *(float4*)(Bs + row * LDP + c4) = *(const float4*)(hn + (size_t)(rowbase + row) * H + c4);
  }
  __syncthreads();
  const int tx = tid & 15, ty = tid >> 4;
  const int c0 = tx * 8, r0 = ty * 2;
  {
    float acc[2][8] = {};
    gemm_acc<2>(As, nw1b, acc, r0, c0);
#pragma unroll
    for (int rr = 0; rr < 2; ++rr)
#pragma unroll
      for (int cc = 0; cc < 8; ++cc)
        Us[(r0 + rr) * LDP + c0 + cc] =
            silu_f(acc[rr][cc] + Bs[(r0 + rr) * LDP + c0 + cc]);
  }
  __syncthreads();
  {
    float acc2[2][8] = {};
    gemm_acc<2>(Us, nw2, acc2, r0, c0);
#pragma unroll
    for (int rr = 0; rr < 2; ++rr)
#pragma unroll
      for (int cc = 0; cc < 8; ++cc) {
        size_t idx = (size_t)(rowbase + r0 + rr) * H + c0 + cc;
        h[idx] += acc2[rr][cc] + nb2[c0 + cc];
      }
  }
}

// dx = pos - pos0, mean-centered over the 64 nodes of each batch, scaled.
__global__ void out_kernel(const float* __restrict__ posF, const float* __restrict__ pos0,
                           const float* __restrict__ scale, float* __restrict__ out) {
  int b = blockIdx.x, i = threadIdx.x;  // 64 threads = 1 wave
  int n = b * NN + i;
  float d0 = posF[n * 3]     - pos0[n * 3];
  float d1 = posF[n * 3 + 1] - pos0[n * 3 + 1];
  float d2v = posF[n * 3 + 2] - pos0[n * 3 + 2];
  float s0 = d0, s1 = d1, s2 = d2v;
  for (int m = 32; m; m >>= 1) {
    s0 += __shfl_xor(s0, m);
    s1 += __shfl_xor(s1, m);
    s2 += __shfl_xor(s2, m);
  }
  const float inv = 1.0f / 64.0f;
  float sc = scale[0];
  out[b * 192 + i * 3]     = (d0 - s0 * inv) * sc;
  out[b * 192 + i * 3 + 1] = (d1 - s1 * inv) * sc;
  out[b * 192 + i * 3 + 2] = (d2v - s2 * inv) * sc;
}

extern "C" void kernel_launch(void* const* d_in, const int* in_sizes, int n_in,
                              void* d_out, int out_size, void* d_ws, size_t ws_size,
                              hipStream_t stream) {
  (void)in_sizes; (void)n_in; (void)out_size; (void)ws_size;
  const float* x   = (const float*)d_in[0];
  const float* ne  = (const float*)d_in[1];
  const float* osc = (const float*)d_in[2];
  const float* ew1 = (const float*)d_in[3];
  const float* eb1 = (const float*)d_in[4];
  const float* ew2 = (const float*)d_in[5];
  const float* eb2 = (const float*)d_in[6];
  const float* cw1 = (const float*)d_in[7];
  const float* cb1 = (const float*)d_in[8];
  const float* cw2 = (const float*)d_in[9];
  const float* nw1 = (const float*)d_in[10];
  const float* nb1 = (const float*)d_in[11];
  const float* nw2 = (const float*)d_in[12];
  const float* nb2 = (const float*)d_in[13];
  // d_in[14] = edge_index: fully-connected structure is generated in-kernel.

  float* ws = (float*)d_ws;
  float* pos0 = ws;                    // 8192*3
  float* posA = pos0 + 24576;
  float* posB = posA + 24576;
  float* h    = posB + 24576;          // 8192*128
  float* hsb  = h   + 1048576;
  float* hdb  = hsb + 1048576;
  float* hnb  = hdb + 1048576;
  float* msgb = hnb + 1048576;
  unsigned short* whi = (unsigned short*)(msgb + 1048576);  // 4L*2mat*16384 ushort
  unsigned short* wlo = whi + 131072;

  init_kernel<<<4096, 256, 0, stream>>>(x, ne, h, pos0, posA);
  prep_kernel<<<512, 256, 0, stream>>>(ew2, cw1, whi, wlo);

  const float* pin[4]  = {posA, posB, posA, posB};
  float*       pout[4] = {posB, posA, posB, posA};

  for (int l = 0; l < 4; ++l) {
    const float* ew1l = ew1 + (size_t)l * 257 * H;
    const unsigned short* w2h = whi + (size_t)l * 2 * 16384;
    const unsigned short* w2l = wlo + (size_t)l * 2 * 16384;
    proj_kernel<<<384, 256, 0, stream>>>(h, ew1l, eb1 + l * H,
                                         nw1 + (size_t)l * 256 * H, nb1 + l * H,
                                         hsb, hdb, hnb);
    edge_kernel<<<8192, 256, 0, stream>>>(hsb, hdb, ew1l + 256 * H,
                                          w2h, w2l, w2h + 16384, w2l + 16384,
                                          eb2 + l * H, cb1 + l * H, cw2 + (size_t)l * H,
                                          pin[l], pout[l], msgb);
    node_kernel<<<256, 256, 0, stream>>>(msgb, hnb,
                                         nw1 + (size_t)l * 256 * H + H * H,
                                         nw2 + (size_t)l * H * H, nb2 + l * H, h);
  }
  out_kernel<<<128, 64, 0, stream>>>(posA, pos0, osc, (float*)d_out);
}